// Round 1
// baseline (285.383 us; speedup 1.0000x reference)
//
#include <hip/hip_runtime.h>
#include <hip/hip_bf16.h>

#define B_  256
#define NH  256
#define NV  512
#define NT  768   // NV + NH

typedef __bf16 bf16x8 __attribute__((ext_vector_type(8)));
typedef float  f32x4  __attribute__((ext_vector_type(4)));

__device__ __forceinline__ __bf16 f2bf(float f) { return static_cast<__bf16>(f); }

// ---------------------------------------------------------------------------
// Kernel A: stream wt once; write bottom-left varvh block + diag block,
// accumulate partial muv sums into ws (4 h-chunks per batch, no atomics).
// ---------------------------------------------------------------------------
__global__ __launch_bounds__(512) void kA(const float* __restrict__ wt,
                                          const float* __restrict__ varh,
                                          const float* __restrict__ muh,
                                          float* __restrict__ var_out,
                                          float* __restrict__ ws_mu) {
    const int b = blockIdx.y;
    const int c = blockIdx.x;            // h-chunk 0..3 (64 rows each)
    const int t = threadIdx.x;           // 0..511 == v
    const float* wtb  = wt + (size_t)b * NH * NV;
    float*       varb = var_out + (size_t)b * NT * NT;

    float acc = 0.f;
    const int h0 = c * 64;
#pragma unroll 4
    for (int hh = 0; hh < 64; ++hh) {
        const int h = h0 + hh;
        const float x  = wtb[h * NV + t];
        const float vh = varh[b * NH + h];
        varb[(size_t)(NV + h) * NT + t] = vh * x;      // bottom-left varvh
        acc += x * muh[b * NH + h];
    }
    if (ws_mu) ws_mu[((b << 2) + c) * NV + t] = acc;

    // diag block rows [h0, h0+64): var[b, 512+r, 512+cc] = (r==cc)? varh : 0
    for (int i = t; i < 64 * NH; i += 512) {
        const int r  = h0 + (i >> 8);
        const int cc = i & 255;
        varb[(size_t)(NV + r) * NT + NV + cc] = (r == cc) ? varh[b * NH + r] : 0.f;
    }
}

// ---------------------------------------------------------------------------
// Fallback mu kernel if ws is too small: muv = b + wt^T @ muh (exact f32)
// ---------------------------------------------------------------------------
__global__ __launch_bounds__(512) void kMu(const float* __restrict__ wt,
                                           const float* __restrict__ muh,
                                           const float* __restrict__ bvec,
                                           float* __restrict__ out) {
    const int b = blockIdx.x;
    const int v = threadIdx.x;
    const float* wtb = wt + (size_t)b * NH * NV;
    float acc = 0.f;
#pragma unroll 4
    for (int h = 0; h < NH; ++h) acc += wtb[h * NV + v] * muh[b * NH + h];
    out[(size_t)b * NT + v] = bvec[b * NV + v] + acc;
}

// ---------------------------------------------------------------------------
// Kernel B: 64x64 LDS transpose of varh*wt -> top-right block.
// Block (0,0,b) also finalizes mu from ws partials and copies muh.
// ---------------------------------------------------------------------------
__global__ __launch_bounds__(256) void kB(const float* __restrict__ wt,
                                          const float* __restrict__ varh,
                                          const float* __restrict__ muh,
                                          const float* __restrict__ bvec,
                                          const float* __restrict__ ws_mu,
                                          float* __restrict__ out) {
    __shared__ float tile[64][65];
    const int b  = blockIdx.z;
    const int v0 = blockIdx.x * 64;
    const int h0 = blockIdx.y * 64;
    const int t  = threadIdx.x;
    const int r  = t >> 4;               // 0..15
    const int c4 = (t & 15) * 4;         // 0,4,...,60
    const float* wtb  = wt + (size_t)b * NH * NV;
    float*       varb = out + (size_t)B_ * NT + (size_t)b * NT * NT;

#pragma unroll
    for (int p = 0; p < 4; ++p) {
        const int h = h0 + r + 16 * p;
        const float vh = varh[b * NH + h];
        const float4 x = *reinterpret_cast<const float4*>(wtb + h * NV + v0 + c4);
        tile[r + 16 * p][c4 + 0] = vh * x.x;
        tile[r + 16 * p][c4 + 1] = vh * x.y;
        tile[r + 16 * p][c4 + 2] = vh * x.z;
        tile[r + 16 * p][c4 + 3] = vh * x.w;
    }
    __syncthreads();
#pragma unroll
    for (int p = 0; p < 4; ++p) {
        const int vrow = v0 + r + 16 * p;
        float4 y;
        y.x = tile[c4 + 0][r + 16 * p];
        y.y = tile[c4 + 1][r + 16 * p];
        y.z = tile[c4 + 2][r + 16 * p];
        y.w = tile[c4 + 3][r + 16 * p];
        *reinterpret_cast<float4*>(varb + (size_t)vrow * NT + NV + h0 + c4) = y;
    }

    if (blockIdx.x == 0 && blockIdx.y == 0) {
        float* mu = out + (size_t)b * NT;
        if (ws_mu) {
            for (int v = t; v < NV; v += 256) {
                float s = bvec[b * NV + v];
                s += ws_mu[((b << 2) + 0) * NV + v] + ws_mu[((b << 2) + 1) * NV + v] +
                     ws_mu[((b << 2) + 2) * NV + v] + ws_mu[((b << 2) + 3) * NV + v];
                mu[v] = s;
            }
        }
        if (t < NH) mu[NV + t] = muh[b * NH + t];
    }
}

// ---------------------------------------------------------------------------
// Kernel C: varv = wt^T * diag(varh) * wt + sig2*I via bf16 MFMA.
// 128x128 tile per block, 4 waves (2x2), K-step 64, mfma_f32_16x16x32_bf16.
// LDS layout: [kouter][chunk][8] bf16, chunk = m ^ ((m>>3)&7) XOR swizzle so
// both ds_write_b128 (staging, m-stride 4) and ds_read_b128 (frags) spread
// across all 32 banks.
// ---------------------------------------------------------------------------
__global__ __launch_bounds__(256) void kC(const float* __restrict__ wt,
                                          const float* __restrict__ varh,
                                          const float* __restrict__ sig2,
                                          float* __restrict__ var_out) {
    __shared__ bf16x8 As[8][128];   // 16 KB
    __shared__ bf16x8 Bs[8][128];   // 16 KB
    __shared__ float  varh_s[NH];   // 1 KB

    const int b  = blockIdx.y;
    const int mt = blockIdx.x >> 2, nt = blockIdx.x & 3;
    const int m0 = mt * 128, n0 = nt * 128;
    const int t    = threadIdx.x;
    const int lane = t & 63;
    const int wid  = t >> 6;
    const int wm   = wid >> 1, wn = wid & 1;

    const float* wtb  = wt + (size_t)b * NH * NV;
    float*       varb = var_out + (size_t)b * NT * NT;

    if (t < NH) varh_s[t] = varh[b * NH + t];

    f32x4 acc[4][4] = {};

    const int mc = t & 31;   // m-chunk (4 floats)
    const int kb = t >> 5;   // kouter 0..7
    __syncthreads();

    for (int st = 0; st < 4; ++st) {
        const int k0 = st * 64;
        f32x4 av[8], bv[8];
        const float* baseA = wtb + (size_t)(k0 + kb * 8) * NV + m0 + 4 * mc;
        const float* baseB = wtb + (size_t)(k0 + kb * 8) * NV + n0 + 4 * mc;
#pragma unroll
        for (int j = 0; j < 8; ++j) {
            av[j] = *reinterpret_cast<const f32x4*>(baseA + j * NV);
            bv[j] = *reinterpret_cast<const f32x4*>(baseB + j * NV);
        }
        float sc[8];
#pragma unroll
        for (int j = 0; j < 8; ++j) sc[j] = varh_s[k0 + kb * 8 + j];

        if (st) __syncthreads();   // previous stage's reads done before overwrite

#pragma unroll
        for (int mj = 0; mj < 4; ++mj) {
            bf16x8 pa, pb;
#pragma unroll
            for (int j = 0; j < 8; ++j) {
                pa[j] = f2bf(av[j][mj]);
                pb[j] = f2bf(bv[j][mj] * sc[j]);
            }
            const int ca = 4 * mc + mj;
            const int ci = ca ^ ((ca >> 3) & 7);
            As[kb][ci] = pa;
            Bs[kb][ci] = pb;
        }
        __syncthreads();

#pragma unroll
        for (int kh = 0; kh < 2; ++kh) {
            const int ko = kh * 4 + (lane >> 4);
            bf16x8 af[4], bfr[4];
#pragma unroll
            for (int f = 0; f < 4; ++f) {
                const int mi = wm * 64 + f * 16 + (lane & 15);
                af[f] = As[ko][mi ^ ((mi >> 3) & 7)];
                const int ni = wn * 64 + f * 16 + (lane & 15);
                bfr[f] = Bs[ko][ni ^ ((ni >> 3) & 7)];
            }
#pragma unroll
            for (int fm = 0; fm < 4; ++fm)
#pragma unroll
                for (int fn = 0; fn < 4; ++fn)
                    acc[fm][fn] = __builtin_amdgcn_mfma_f32_16x16x32_bf16(
                        af[fm], bfr[fn], acc[fm][fn], 0, 0, 0);
        }
    }

    const float s2 = sig2[b];
#pragma unroll
    for (int fm = 0; fm < 4; ++fm) {
#pragma unroll
        for (int fn = 0; fn < 4; ++fn) {
            const int row = m0 + wm * 64 + fm * 16 + ((lane >> 4) << 2);
            const int col = n0 + wn * 64 + fn * 16 + (lane & 15);
#pragma unroll
            for (int r = 0; r < 4; ++r) {
                float v = acc[fm][fn][r];
                if (row + r == col) v += s2;
                varb[(size_t)(row + r) * NT + col] = v;
            }
        }
    }
}

// ---------------------------------------------------------------------------
extern "C" void kernel_launch(void* const* d_in, const int* in_sizes, int n_in,
                              void* d_out, int out_size, void* d_ws, size_t ws_size,
                              hipStream_t stream) {
    (void)in_sizes; (void)n_in; (void)out_size;
    const float* wt   = (const float*)d_in[0];
    const float* varh = (const float*)d_in[1];
    const float* sig2 = (const float*)d_in[2];
    const float* bvec = (const float*)d_in[3];
    const float* muh  = (const float*)d_in[4];
    float* out     = (float*)d_out;
    float* var_out = out + (size_t)B_ * NT;

    const bool use_ws = ws_size >= (size_t)B_ * 4 * NV * sizeof(float);
    float* ws_mu = use_ws ? (float*)d_ws : nullptr;

    kA<<<dim3(4, B_), 512, 0, stream>>>(wt, varh, muh, var_out, ws_mu);
    if (!use_ws) kMu<<<B_, 512, 0, stream>>>(wt, muh, bvec, out);
    kB<<<dim3(8, 4, B_), 256, 0, stream>>>(wt, varh, muh, bvec, ws_mu, out);
    kC<<<dim3(16, B_), 256, 0, stream>>>(wt, varh, sig2, var_out);
}

// Round 2
// 211.828 us; speedup vs baseline: 1.3472x; 1.3472x over previous
//
#include <hip/hip_runtime.h>
#include <hip/hip_bf16.h>

#define B_  256
#define NH  256
#define NV  512
#define NT  768   // NV + NH
#define TILES_PER_BATCH 28   // 16 varv MFMA + 8 fused-copy + 4 diag

typedef __bf16 bf16x8 __attribute__((ext_vector_type(8)));
typedef float  f32x4  __attribute__((ext_vector_type(4)));

__device__ __forceinline__ __bf16 f2bf(float f) { return static_cast<__bf16>(f); }

// One fused kernel. Block types per batch (tile = 0..27):
//   tile 0..15 : varv 128x128 MFMA tile (mt=tile>>2, nt=tile&3); nt==0 blocks
//                also compute muv (exact f32) for their 128 columns.
//   tile 16..23: fused copy tile — read wt 128x128 once, write bottom-left
//                varvh (coalesced) AND top-right varvh^T (LDS transpose).
//   tile 24..27: diag block 128x128 (zeros + varh diagonal); tile 24 also
//                copies muh into mu.
// XCD mapping: bid&7 == XCD (round-robin heuristic); all 28 blocks of a batch
// share one XCD so wt(batch) is fetched into exactly one L2.
__global__ __launch_bounds__(256) void fused(const float* __restrict__ wt,
                                             const float* __restrict__ varh,
                                             const float* __restrict__ sig2,
                                             const float* __restrict__ bvec,
                                             const float* __restrict__ muh,
                                             float* __restrict__ out) {
    __shared__ __align__(16) char smem[38 * 1024];

    const int bid  = blockIdx.x;
    const int q    = bid >> 3;
    const int b    = (bid & 7) * 32 + q / TILES_PER_BATCH;
    const int tile = q % TILES_PER_BATCH;
    const int t    = threadIdx.x;

    const float* wtb  = wt + (size_t)b * NH * NV;
    float* mu   = out + (size_t)b * NT;
    float* varb = out + (size_t)B_ * NT + (size_t)b * NT * NT;

    if (tile < 16) {
        // ------------------- varv MFMA tile -------------------
        bf16x8 (*As)[128]  = (bf16x8(*)[128])(smem);
        bf16x8 (*Bs)[128]  = (bf16x8(*)[128])(smem + 16 * 1024);
        float*  varh_s     = (float*)(smem + 32 * 1024);
        float*  muh_s      = (float*)(smem + 33 * 1024);
        float (*red)[128]  = (float(*)[128])(smem + 34 * 1024);

        const int mt = tile >> 2, nt = tile & 3;
        const int m0 = mt * 128, n0 = nt * 128;
        const int lane = t & 63, wid = t >> 6;
        const int wm = wid >> 1, wn = wid & 1;
        const int mc = t & 31;   // m-chunk (4 floats)
        const int kb = t >> 5;   // k-chunk 0..7

        varh_s[t] = varh[b * NH + t];   // 256 threads == NH
        muh_s[t]  = muh[b * NH + t];

        f32x4 acc[4][4] = {};
        float acc_mu[4] = {0.f, 0.f, 0.f, 0.f};
        __syncthreads();

        for (int st = 0; st < 4; ++st) {
            const int k0 = st * 64;
            f32x4 av[8], bv[8];
            const float* baseA = wtb + (size_t)(k0 + kb * 8) * NV + m0 + 4 * mc;
            const float* baseB = wtb + (size_t)(k0 + kb * 8) * NV + n0 + 4 * mc;
#pragma unroll
            for (int j = 0; j < 8; ++j) {
                av[j] = *reinterpret_cast<const f32x4*>(baseA + j * NV);
                bv[j] = *reinterpret_cast<const f32x4*>(baseB + j * NV);
            }
            float sc[8];
#pragma unroll
            for (int j = 0; j < 8; ++j) sc[j] = varh_s[k0 + kb * 8 + j];

            if (nt == 0) {   // exact-f32 muv partial sums (block-uniform branch)
#pragma unroll
                for (int j = 0; j < 8; ++j) {
                    const float mh = muh_s[k0 + kb * 8 + j];
#pragma unroll
                    for (int mj = 0; mj < 4; ++mj) acc_mu[mj] += av[j][mj] * mh;
                }
            }

            if (st) __syncthreads();   // prev stage's LDS reads done

#pragma unroll
            for (int mj = 0; mj < 4; ++mj) {
                bf16x8 pa, pb;
#pragma unroll
                for (int j = 0; j < 8; ++j) {
                    pa[j] = f2bf(av[j][mj]);
                    pb[j] = f2bf(bv[j][mj] * sc[j]);
                }
                const int ca = 4 * mc + mj;
                const int ci = ca ^ ((ca >> 3) & 7);
                As[kb][ci] = pa;
                Bs[kb][ci] = pb;
            }
            __syncthreads();

#pragma unroll
            for (int kh = 0; kh < 2; ++kh) {
                const int ko = kh * 4 + (lane >> 4);
                bf16x8 af[4], bfr[4];
#pragma unroll
                for (int f = 0; f < 4; ++f) {
                    const int mi = wm * 64 + f * 16 + (lane & 15);
                    af[f] = As[ko][mi ^ ((mi >> 3) & 7)];
                    const int ni = wn * 64 + f * 16 + (lane & 15);
                    bfr[f] = Bs[ko][ni ^ ((ni >> 3) & 7)];
                }
#pragma unroll
                for (int fm = 0; fm < 4; ++fm)
#pragma unroll
                    for (int fn = 0; fn < 4; ++fn)
                        acc[fm][fn] = __builtin_amdgcn_mfma_f32_16x16x32_bf16(
                            af[fm], bfr[fn], acc[fm][fn], 0, 0, 0);
            }
        }

        const float s2 = sig2[b];
#pragma unroll
        for (int fm = 0; fm < 4; ++fm) {
#pragma unroll
            for (int fn = 0; fn < 4; ++fn) {
                const int row = m0 + wm * 64 + fm * 16 + ((lane >> 4) << 2);
                const int col = n0 + wn * 64 + fn * 16 + (lane & 15);
#pragma unroll
                for (int r = 0; r < 4; ++r) {
                    float v = acc[fm][fn][r];
                    if (row + r == col) v += s2;
                    varb[(size_t)(row + r) * NT + col] = v;
                }
            }
        }

        if (nt == 0) {   // finalize muv for columns m0..m0+127
#pragma unroll
            for (int mj = 0; mj < 4; ++mj) red[kb][4 * mc + mj] = acc_mu[mj];
            __syncthreads();
            if (t < 128) {
                float s = 0.f;
#pragma unroll
                for (int k = 0; k < 8; ++k) s += red[k][t];
                mu[m0 + t] = bvec[b * NV + m0 + t] + s;
            }
        }
    } else if (tile < 24) {
        // ------------------- fused copy tile (bottom-left + top-right) ------
        const int idx = tile - 16;
        const int hi = idx >> 2, vj = idx & 3;       // hi 0..1, vj 0..3
        const int h0 = hi * 128, v0 = vj * 128;
        float (*tl)[65] = (float(*)[65])smem;        // 64x65 f32, 16.6 KB
        const int r  = t >> 4;          // 0..15
        const int c4 = (t & 15) * 4;    // 0,4,...,60

        for (int sub = 0; sub < 4; ++sub) {
            const int sh = (sub >> 1) * 64, sv = (sub & 1) * 64;
            if (sub) __syncthreads();    // prev sub's reads done before overwrite
#pragma unroll
            for (int p = 0; p < 4; ++p) {
                const int h = h0 + sh + r + 16 * p;
                const float vh = varh[b * NH + h];
                f32x4 x = *reinterpret_cast<const f32x4*>(
                    wtb + (size_t)h * NV + v0 + sv + c4);
                x *= vh;
                *reinterpret_cast<f32x4*>(
                    varb + (size_t)(NV + h) * NT + v0 + sv + c4) = x;  // bottom-left
                tl[r + 16 * p][c4 + 0] = x[0];
                tl[r + 16 * p][c4 + 1] = x[1];
                tl[r + 16 * p][c4 + 2] = x[2];
                tl[r + 16 * p][c4 + 3] = x[3];
            }
            __syncthreads();
#pragma unroll
            for (int p = 0; p < 4; ++p) {
                const int vrow = v0 + sv + r + 16 * p;
                f32x4 y;
                y[0] = tl[c4 + 0][r + 16 * p];
                y[1] = tl[c4 + 1][r + 16 * p];
                y[2] = tl[c4 + 2][r + 16 * p];
                y[3] = tl[c4 + 3][r + 16 * p];
                *reinterpret_cast<f32x4*>(
                    varb + (size_t)vrow * NT + NV + h0 + sh + c4) = y;  // top-right
            }
        }
    } else {
        // ------------------- diag block -------------------
        const int d  = tile - 24;
        const int di = d >> 1, dj = d & 1;
        const int r0 = NV + di * 128, c0 = NV + dj * 128;
        const int rr = t >> 5;           // 0..7
        const int c4 = (t & 31) * 4;     // 0..124
#pragma unroll
        for (int p = 0; p < 16; ++p) {
            const int row = rr + 8 * p;  // 0..127
            f32x4 v = {0.f, 0.f, 0.f, 0.f};
            if (di == dj) {
                const int dpos = row - c4;
                if (dpos >= 0 && dpos < 4) v[dpos] = varh[b * NH + di * 128 + row];
            }
            *reinterpret_cast<f32x4*>(varb + (size_t)(r0 + row) * NT + c0 + c4) = v;
        }
        if (d == 0) mu[NV + t] = muh[b * NH + t];   // 256 threads == NH
    }
}

// ---------------------------------------------------------------------------
extern "C" void kernel_launch(void* const* d_in, const int* in_sizes, int n_in,
                              void* d_out, int out_size, void* d_ws, size_t ws_size,
                              hipStream_t stream) {
    (void)in_sizes; (void)n_in; (void)out_size; (void)d_ws; (void)ws_size;
    const float* wt   = (const float*)d_in[0];
    const float* varh = (const float*)d_in[1];
    const float* sig2 = (const float*)d_in[2];
    const float* bvec = (const float*)d_in[3];
    const float* muh  = (const float*)d_in[4];
    float* out = (float*)d_out;

    fused<<<B_ * TILES_PER_BATCH, 256, 0, stream>>>(wt, varh, sig2, bvec, muh, out);
}

// Round 3
// 162.448 us; speedup vs baseline: 1.7568x; 1.3040x over previous
//
#include <hip/hip_runtime.h>
#include <hip/hip_bf16.h>

#define B_  256
#define NH  256
#define NV  512
#define NT  768   // NV + NH
#define TILES_PER_BATCH 22   // 10 varv MFMA (upper tri) + 8 fused-copy + 4 diag

typedef __bf16 bf16x8 __attribute__((ext_vector_type(8)));
typedef float  f32x4  __attribute__((ext_vector_type(4)));

__device__ __forceinline__ __bf16 f2bf(float f) { return static_cast<__bf16>(f); }

// varv = wt^T diag(varh) wt + sig2*I is SYMMETRIC: compute only mt<=nt tiles.
//   tile 0..3  : diag MFMA tile (mt==nt) — A panel only (B = scaled A),
//                also computes exact-f32 muv for its 128 columns.
//   tile 4..9  : off-diag MFMA tile — writes tile AND its transpose mirror.
//   tile 10..17: fused copy tile — read wt 128x128 once, write bottom-left
//                varvh (coalesced) AND top-right varvh^T (LDS transpose).
//   tile 18..21: diag block (zeros + varh diagonal); tile 18 copies muh.
// XCD mapping: bid&7 == XCD; all 22 blocks of a batch share one XCD so
// wt(batch) lives in exactly one L2.
__global__ __launch_bounds__(256) void fused(const float* __restrict__ wt,
                                             const float* __restrict__ varh,
                                             const float* __restrict__ sig2,
                                             const float* __restrict__ bvec,
                                             const float* __restrict__ muh,
                                             float* __restrict__ out) {
    __shared__ __align__(16) char smem[38 * 1024];

    const int bid  = blockIdx.x;
    const int q    = bid >> 3;
    const int b    = (bid & 7) * 32 + q / TILES_PER_BATCH;
    const int tile = q % TILES_PER_BATCH;
    const int t    = threadIdx.x;

    const float* wtb  = wt + (size_t)b * NH * NV;
    float* mu   = out + (size_t)b * NT;
    float* varb = out + (size_t)B_ * NT + (size_t)b * NT * NT;

    if (tile < 10) {
        // ------------------- varv MFMA tile (upper triangle) -------------------
        static const signed char MT[10] = {0,1,2,3, 0,0,0,1,1,2};
        static const signed char NTc[10] = {0,1,2,3, 1,2,3,2,3,3};
        const int mt = MT[tile], nt = NTc[tile];
        const bool diag = (mt == nt);

        bf16x8 (*As)[128]  = (bf16x8(*)[128])(smem);
        bf16x8 (*Bs)[128]  = (bf16x8(*)[128])(smem + 16 * 1024);
        float*  varh_s     = (float*)(smem + 32 * 1024);
        float*  muh_s      = (float*)(smem + 33 * 1024);
        float (*red)[128]  = (float(*)[128])(smem + 34 * 1024);

        const int m0 = mt * 128, n0 = nt * 128;
        const int lane = t & 63, wid = t >> 6;
        const int wm = wid >> 1, wn = wid & 1;
        const int mc = t & 31;   // m-chunk (4 floats)
        const int kb = t >> 5;   // k-chunk 0..7

        varh_s[t] = varh[b * NH + t];   // 256 threads == NH
        muh_s[t]  = muh[b * NH + t];

        f32x4 acc[4][4] = {};
        float acc_mu[4] = {0.f, 0.f, 0.f, 0.f};
        __syncthreads();

        for (int st = 0; st < 4; ++st) {
            const int k0 = st * 64;
            f32x4 av[8], bv[8];
            const float* baseA = wtb + (size_t)(k0 + kb * 8) * NV + m0 + 4 * mc;
#pragma unroll
            for (int j = 0; j < 8; ++j)
                av[j] = *reinterpret_cast<const f32x4*>(baseA + j * NV);
            if (!diag) {
                const float* baseB = wtb + (size_t)(k0 + kb * 8) * NV + n0 + 4 * mc;
#pragma unroll
                for (int j = 0; j < 8; ++j)
                    bv[j] = *reinterpret_cast<const f32x4*>(baseB + j * NV);
            } else {
#pragma unroll
                for (int j = 0; j < 8; ++j) bv[j] = av[j];
            }
            float sc[8];
#pragma unroll
            for (int j = 0; j < 8; ++j) sc[j] = varh_s[k0 + kb * 8 + j];

            if (diag) {   // exact-f32 muv partial sums (block-uniform branch)
#pragma unroll
                for (int j = 0; j < 8; ++j) {
                    const float mh = muh_s[k0 + kb * 8 + j];
#pragma unroll
                    for (int mj = 0; mj < 4; ++mj) acc_mu[mj] += av[j][mj] * mh;
                }
            }

            if (st) __syncthreads();   // prev stage's LDS reads done

#pragma unroll
            for (int mj = 0; mj < 4; ++mj) {
                bf16x8 pa, pb;
#pragma unroll
                for (int j = 0; j < 8; ++j) {
                    pa[j] = f2bf(av[j][mj]);
                    pb[j] = f2bf(bv[j][mj] * sc[j]);
                }
                const int ca = 4 * mc + mj;
                const int ci = ca ^ ((ca >> 3) & 7);
                As[kb][ci] = pa;
                Bs[kb][ci] = pb;
            }
            __syncthreads();

#pragma unroll
            for (int kh = 0; kh < 2; ++kh) {
                const int ko = kh * 4 + (lane >> 4);
                bf16x8 af[4], bfr[4];
#pragma unroll
                for (int f = 0; f < 4; ++f) {
                    const int mi = wm * 64 + f * 16 + (lane & 15);
                    af[f] = As[ko][mi ^ ((mi >> 3) & 7)];
                    const int ni = wn * 64 + f * 16 + (lane & 15);
                    bfr[f] = Bs[ko][ni ^ ((ni >> 3) & 7)];
                }
#pragma unroll
                for (int fm = 0; fm < 4; ++fm)
#pragma unroll
                    for (int fn = 0; fn < 4; ++fn)
                        acc[fm][fn] = __builtin_amdgcn_mfma_f32_16x16x32_bf16(
                            af[fm], bfr[fn], acc[fm][fn], 0, 0, 0);
            }
        }

        const float s2 = sig2[b];
#pragma unroll
        for (int fm = 0; fm < 4; ++fm) {
#pragma unroll
            for (int fn = 0; fn < 4; ++fn) {
                const int row = m0 + wm * 64 + fm * 16 + ((lane >> 4) << 2);
                const int col = n0 + wn * 64 + fn * 16 + (lane & 15);
#pragma unroll
                for (int r = 0; r < 4; ++r) {
                    float v = acc[fm][fn][r];
                    if (row + r == col) v += s2;
                    varb[(size_t)(row + r) * NT + col] = v;
                }
                if (!diag) {   // mirror: varv[col][row..row+3] = same 4 values
                    *reinterpret_cast<f32x4*>(varb + (size_t)col * NT + row) =
                        acc[fm][fn];
                }
            }
        }

        if (diag) {   // finalize muv for columns m0..m0+127
#pragma unroll
            for (int mj = 0; mj < 4; ++mj) red[kb][4 * mc + mj] = acc_mu[mj];
            __syncthreads();
            if (t < 128) {
                float s = 0.f;
#pragma unroll
                for (int k = 0; k < 8; ++k) s += red[k][t];
                mu[m0 + t] = bvec[b * NV + m0 + t] + s;
            }
        }
    } else if (tile < 18) {
        // ------------------- fused copy tile (bottom-left + top-right) ------
        const int idx = tile - 10;
        const int hi = idx >> 2, vj = idx & 3;       // hi 0..1, vj 0..3
        const int h0 = hi * 128, v0 = vj * 128;
        float (*tl)[65] = (float(*)[65])smem;        // 64x65 f32, 16.6 KB
        const int r  = t >> 4;          // 0..15
        const int c4 = (t & 15) * 4;    // 0,4,...,60

        for (int sub = 0; sub < 4; ++sub) {
            const int sh = (sub >> 1) * 64, sv = (sub & 1) * 64;
            if (sub) __syncthreads();    // prev sub's reads done before overwrite
#pragma unroll
            for (int p = 0; p < 4; ++p) {
                const int h = h0 + sh + r + 16 * p;
                const float vh = varh[b * NH + h];
                f32x4 x = *reinterpret_cast<const f32x4*>(
                    wtb + (size_t)h * NV + v0 + sv + c4);
                x *= vh;
                *reinterpret_cast<f32x4*>(
                    varb + (size_t)(NV + h) * NT + v0 + sv + c4) = x;  // bottom-left
                tl[r + 16 * p][c4 + 0] = x[0];
                tl[r + 16 * p][c4 + 1] = x[1];
                tl[r + 16 * p][c4 + 2] = x[2];
                tl[r + 16 * p][c4 + 3] = x[3];
            }
            __syncthreads();
#pragma unroll
            for (int p = 0; p < 4; ++p) {
                const int vrow = v0 + sv + r + 16 * p;
                f32x4 y;
                y[0] = tl[c4 + 0][r + 16 * p];
                y[1] = tl[c4 + 1][r + 16 * p];
                y[2] = tl[c4 + 2][r + 16 * p];
                y[3] = tl[c4 + 3][r + 16 * p];
                *reinterpret_cast<f32x4*>(
                    varb + (size_t)vrow * NT + NV + h0 + sh + c4) = y;  // top-right
            }
        }
    } else {
        // ------------------- diag block -------------------
        const int d  = tile - 18;
        const int di = d >> 1, dj = d & 1;
        const int r0 = NV + di * 128, c0 = NV + dj * 128;
        const int rr = t >> 5;           // 0..7
        const int c4 = (t & 31) * 4;     // 0..124
#pragma unroll
        for (int p = 0; p < 16; ++p) {
            const int row = rr + 8 * p;  // 0..127
            f32x4 v = {0.f, 0.f, 0.f, 0.f};
            if (di == dj) {
                const int dpos = row - c4;
                if (dpos >= 0 && dpos < 4) v[dpos] = varh[b * NH + di * 128 + row];
            }
            *reinterpret_cast<f32x4*>(varb + (size_t)(r0 + row) * NT + c0 + c4) = v;
        }
        if (d == 0) mu[NV + t] = muh[b * NH + t];   // 256 threads == NH
    }
}

// ---------------------------------------------------------------------------
extern "C" void kernel_launch(void* const* d_in, const int* in_sizes, int n_in,
                              void* d_out, int out_size, void* d_ws, size_t ws_size,
                              hipStream_t stream) {
    (void)in_sizes; (void)n_in; (void)out_size; (void)d_ws; (void)ws_size;
    const float* wt   = (const float*)d_in[0];
    const float* varh = (const float*)d_in[1];
    const float* sig2 = (const float*)d_in[2];
    const float* bvec = (const float*)d_in[3];
    const float* muh  = (const float*)d_in[4];
    float* out = (float*)d_out;

    fused<<<B_ * TILES_PER_BATCH, 256, 0, stream>>>(wt, varh, sig2, bvec, muh, out);
}

// Round 4
// 161.861 us; speedup vs baseline: 1.7631x; 1.0036x over previous
//
#include <hip/hip_runtime.h>
#include <hip/hip_bf16.h>

#define B_  256
#define NH  256
#define NV  512
#define NT  768   // NV + NH
#define TPB 9     // 3 varv MFMA (2 diag + 1 offdiag) + 4 copy bands + 2 diag-region

typedef __bf16 bf16x8 __attribute__((ext_vector_type(8)));
typedef float  f32x4  __attribute__((ext_vector_type(4)));

__device__ __forceinline__ __bf16 f2bf(float f) { return static_cast<__bf16>(f); }

// varv = wt^T diag(varh) wt + sig2*I (symmetric). Per batch, 9 blocks @512thr:
//   tile 0,1 : diag 256^2 MFMA tile (B = scaled A, one panel read);
//              also computes exact-f32 muv for its 256 columns.
//   tile 2   : off-diag 256^2 MFMA tile; writes tile AND transpose mirror.
//   tile 3..6: copy band (64 h-rows x 512 v): read varh*wt once, write
//              bottom-left (coalesced) AND top-right (dual 64x65 LDS transpose).
//   tile 7,8 : diag-region rows (zeros + varh diagonal); tile 7 copies muh.
// XCD mapping: bid&7 == XCD; all 9 blocks of a batch share one XCD.
__global__ __launch_bounds__(512) void fused(const float* __restrict__ wt,
                                             const float* __restrict__ varh,
                                             const float* __restrict__ sig2,
                                             const float* __restrict__ bvec,
                                             const float* __restrict__ muh,
                                             float* __restrict__ out) {
    __shared__ __align__(16) char smem[76 * 1024];

    const int bid  = blockIdx.x;
    const int q    = bid >> 3;
    const int b    = (bid & 7) * 32 + q / TPB;
    const int tile = q % TPB;
    const int t    = threadIdx.x;

    const float* wtb  = wt + (size_t)b * NH * NV;
    float* mu   = out + (size_t)b * NT;
    float* varb = out + (size_t)B_ * NT + (size_t)b * NT * NT;

    if (tile < 3) {
        // ------------------- varv 256x256 MFMA tile -------------------
        const int  mt   = (tile == 1);
        const int  nt   = (tile != 0);
        const bool diag = (tile < 2);

        bf16x8 (*As)[256] = (bf16x8(*)[256])(smem);             // 32 KB
        bf16x8 (*Bs)[256] = (bf16x8(*)[256])(smem + 32 * 1024); // 32 KB
        float*  varh_s    = (float*)(smem + 64 * 1024);
        float*  muh_s     = (float*)(smem + 65 * 1024);
        float (*red)[256] = (float(*)[256])(smem + 66 * 1024);  // 8 KB

        const int m0 = mt * 256, n0 = nt * 256;
        const int lane = t & 63, wid = t >> 6;
        const int wm = wid >> 2, wn = wid & 3;   // wave tile 128x64
        const int mc = t & 63;   // staging m-chunk (4 floats)
        const int kb = t >> 6;   // staging k-chunk 0..7 (8 k-rows each)

        if (t < NH) { varh_s[t] = varh[b * NH + t]; muh_s[t] = muh[b * NH + t]; }

        f32x4 acc[8][4] = {};
        float acc_mu[4] = {0.f, 0.f, 0.f, 0.f};
        __syncthreads();

        for (int st = 0; st < 4; ++st) {
            const int k0 = st * 64;
            f32x4 av[8], bv[8];
            const float* baseA = wtb + (size_t)(k0 + kb * 8) * NV + m0 + 4 * mc;
#pragma unroll
            for (int j = 0; j < 8; ++j)
                av[j] = *reinterpret_cast<const f32x4*>(baseA + j * NV);
            if (!diag) {
                const float* baseB = wtb + (size_t)(k0 + kb * 8) * NV + n0 + 4 * mc;
#pragma unroll
                for (int j = 0; j < 8; ++j)
                    bv[j] = *reinterpret_cast<const f32x4*>(baseB + j * NV);
            }
            float sc[8];
#pragma unroll
            for (int j = 0; j < 8; ++j) sc[j] = varh_s[k0 + kb * 8 + j];

            if (diag) {   // exact-f32 muv partials (block-uniform branch)
#pragma unroll
                for (int j = 0; j < 8; ++j) {
                    const float mh = muh_s[k0 + kb * 8 + j];
#pragma unroll
                    for (int mj = 0; mj < 4; ++mj) acc_mu[mj] += av[j][mj] * mh;
                }
            }

            if (st) __syncthreads();   // prev stage's LDS reads done

#pragma unroll
            for (int mj = 0; mj < 4; ++mj) {
                bf16x8 pa, pb;
#pragma unroll
                for (int j = 0; j < 8; ++j) {
                    const float a  = av[j][mj];
                    const float bb = diag ? a : bv[j][mj];
                    pa[j] = f2bf(a);
                    pb[j] = f2bf(bb * sc[j]);
                }
                const int ca = 4 * mc + mj;
                const int ci = ca ^ ((ca >> 3) & 7);
                As[kb][ci] = pa;
                Bs[kb][ci] = pb;
            }
            __syncthreads();

#pragma unroll
            for (int kh = 0; kh < 2; ++kh) {
                const int ko = kh * 4 + (lane >> 4);
                bf16x8 af[8], bf4[4];
#pragma unroll
                for (int f = 0; f < 8; ++f) {
                    const int mi = wm * 128 + f * 16 + (lane & 15);
                    af[f] = As[ko][mi ^ ((mi >> 3) & 7)];
                }
#pragma unroll
                for (int f = 0; f < 4; ++f) {
                    const int ni = wn * 64 + f * 16 + (lane & 15);
                    bf4[f] = Bs[ko][ni ^ ((ni >> 3) & 7)];
                }
#pragma unroll
                for (int fm = 0; fm < 8; ++fm)
#pragma unroll
                    for (int fn = 0; fn < 4; ++fn)
                        acc[fm][fn] = __builtin_amdgcn_mfma_f32_16x16x32_bf16(
                            af[fm], bf4[fn], acc[fm][fn], 0, 0, 0);
            }
        }

        const float s2 = sig2[b];
#pragma unroll
        for (int fm = 0; fm < 8; ++fm) {
#pragma unroll
            for (int fn = 0; fn < 4; ++fn) {
                const int row = m0 + wm * 128 + fm * 16 + ((lane >> 4) << 2);
                const int col = n0 + wn * 64 + fn * 16 + (lane & 15);
#pragma unroll
                for (int r = 0; r < 4; ++r) {
                    float v = acc[fm][fn][r];
                    if (row + r == col) v += s2;
                    varb[(size_t)(row + r) * NT + col] = v;
                }
                if (!diag) {   // mirror: varv[col][row..row+3]
                    *reinterpret_cast<f32x4*>(varb + (size_t)col * NT + row) =
                        acc[fm][fn];
                }
            }
        }

        if (diag) {   // finalize muv for columns m0..m0+255
#pragma unroll
            for (int mj = 0; mj < 4; ++mj) red[kb][4 * mc + mj] = acc_mu[mj];
            __syncthreads();
            if (t < 256) {
                float s = 0.f;
#pragma unroll
                for (int k = 0; k < 8; ++k) s += red[k][t];
                mu[m0 + t] = bvec[b * NV + m0 + t] + s;
            }
        }
    } else if (tile < 7) {
        // ------------- copy band: 64 h-rows x 512 v (BL + TR) -------------
        const int h0 = (tile - 3) * 64;
        float (*tl)[64][65] = (float(*)[64][65])smem;   // 2 x 64x65 f32, 33 KB
        const int sub = t >> 8;          // 0..1 (two subtiles in parallel)
        const int tt  = t & 255;
        const int r   = tt >> 4;         // 0..15
        const int c4  = (tt & 15) * 4;   // 0..60

        for (int iter = 0; iter < 4; ++iter) {
            const int v0 = iter * 128 + sub * 64;
            if (iter) __syncthreads();   // prev iter's reads done
#pragma unroll
            for (int p = 0; p < 4; ++p) {
                const int h = h0 + r + 16 * p;
                const float vh = varh[b * NH + h];
                f32x4 x = *reinterpret_cast<const f32x4*>(
                    wtb + (size_t)h * NV + v0 + c4);
                x *= vh;
                *reinterpret_cast<f32x4*>(
                    varb + (size_t)(NV + h) * NT + v0 + c4) = x;   // bottom-left
                tl[sub][r + 16 * p][c4 + 0] = x[0];
                tl[sub][r + 16 * p][c4 + 1] = x[1];
                tl[sub][r + 16 * p][c4 + 2] = x[2];
                tl[sub][r + 16 * p][c4 + 3] = x[3];
            }
            __syncthreads();
#pragma unroll
            for (int p = 0; p < 4; ++p) {
                const int vrow = v0 + r + 16 * p;
                f32x4 y;
                y[0] = tl[sub][c4 + 0][r + 16 * p];
                y[1] = tl[sub][c4 + 1][r + 16 * p];
                y[2] = tl[sub][c4 + 2][r + 16 * p];
                y[3] = tl[sub][c4 + 3][r + 16 * p];
                *reinterpret_cast<f32x4*>(
                    varb + (size_t)vrow * NT + NV + h0 + c4) = y;  // top-right
            }
        }
    } else {
        // ------------------- diag-region rows (128 x 256) -------------------
        const int d  = tile - 7;          // 0..1
        const int r0 = NV + d * 128;
        const int rr = t >> 6;            // 0..7
        const int c4 = (t & 63) * 4;      // 0..252
#pragma unroll
        for (int p = 0; p < 16; ++p) {
            const int row = rr + 8 * p;   // 0..127
            const int g   = d * 128 + row;
            const int dpos = g - c4;
            const float val = (dpos >= 0 && dpos < 4) ? varh[b * NH + g] : 0.f;
            f32x4 v;
            v[0] = (dpos == 0) ? val : 0.f;
            v[1] = (dpos == 1) ? val : 0.f;
            v[2] = (dpos == 2) ? val : 0.f;
            v[3] = (dpos == 3) ? val : 0.f;
            *reinterpret_cast<f32x4*>(varb + (size_t)(r0 + row) * NT + NV + c4) = v;
        }
        if (d == 0 && t < NH) mu[NV + t] = muh[b * NH + t];
    }
}

// ---------------------------------------------------------------------------
extern "C" void kernel_launch(void* const* d_in, const int* in_sizes, int n_in,
                              void* d_out, int out_size, void* d_ws, size_t ws_size,
                              hipStream_t stream) {
    (void)in_sizes; (void)n_in; (void)out_size; (void)d_ws; (void)ws_size;
    const float* wt   = (const float*)d_in[0];
    const float* varh = (const float*)d_in[1];
    const float* sig2 = (const float*)d_in[2];
    const float* bvec = (const float*)d_in[3];
    const float* muh  = (const float*)d_in[4];
    float* out = (float*)d_out;

    fused<<<B_ * TPB, 512, 0, stream>>>(wt, varh, sig2, bvec, muh, out);
}